// Round 4
// baseline (248.835 us; speedup 1.0000x reference)
//
#include <hip/hip_runtime.h>

typedef __bf16 bf16x8 __attribute__((ext_vector_type(8)));
typedef float f32x4 __attribute__((ext_vector_type(4)));

#define EPS_F 1e-5f

// direct global -> LDS DMA, 16 B per lane. LDS dest is wave-uniform base +
// lane*16 (m104); global src is per-lane.
__device__ __forceinline__ void gload_lds16(const void* g, void* l) {
    __builtin_amdgcn_global_load_lds(
        (const __attribute__((address_space(1))) unsigned int*)g,
        (__attribute__((address_space(3))) unsigned int*)l, 16, 0, 0);
}

// -------------------------------------------------------------------------
// k_pack_x: x[b][c][p] fp32 -> x_t2[b][kt][p][cc] bf16  (kt = c/32, cc = c%32)
// K-tiled layout: each GEMM A-tile (b, kt, 112 p-rows) is contiguous.
// grid (128 b, 32 kt), block 256. LDS transpose tile 32c x 196p.
// -------------------------------------------------------------------------
__global__ __launch_bounds__(256) void k_pack_x(
    const float* __restrict__ x, __bf16* __restrict__ xt)
{
    __shared__ float xs[32][204];            // pad 204 (float4-aligned rows)
    const int b = blockIdx.x, kt = blockIdx.y, tid = threadIdx.x;
    const float* src = x + ((size_t)b * 1024 + (size_t)kt * 32) * 196;
#pragma unroll
    for (int k = 0; k < 7; k++) {
        const int i4 = tid + k * 256;
        if (i4 < 1568) {                     // 32 c * 49 float4
            const int c = i4 / 49, pq = i4 % 49;
            const float4 v = *(const float4*)(src + c * 196 + pq * 4);
            *(float4*)&xs[c][pq * 4] = v;
        }
    }
    __syncthreads();
    __bf16* dst = xt + (size_t)(b * 32 + kt) * 196 * 32;
#pragma unroll
    for (int k = 0; k < 4; k++) {
        const int it = tid + k * 256;
        if (it < 784) {                      // 196 p * 4 groups of 8 c
            const int p = it >> 2, g = it & 3;
            bf16x8 o;
#pragma unroll
            for (int j = 0; j < 8; j++) o[j] = (__bf16)xs[g * 8 + j][p];
            *(bf16x8*)(dst + (size_t)p * 32 + g * 8) = o;   // fully contiguous
        }
    }
}

// -------------------------------------------------------------------------
// k_pack_w1: w1[r][c] fp32 -> w1_t[kt][r][cc] bf16. grid 128, block 256.
// -------------------------------------------------------------------------
__global__ __launch_bounds__(256) void k_pack_w1(
    const float* __restrict__ w1, __bf16* __restrict__ w1t)
{
    const int it = blockIdx.x * 256 + threadIdx.x;   // 32768 ushort8 groups
    const int kt = it >> 10, rem = it & 1023, r = rem >> 2, g = rem & 3;
    const float* s = w1 + (size_t)r * 1024 + kt * 32 + g * 8;
    bf16x8 o;
#pragma unroll
    for (int j = 0; j < 8; j++) o[j] = (__bf16)s[j];
    *(bf16x8*)(w1t + (size_t)it * 8) = o;
}

// -------------------------------------------------------------------------
// Kernel 1 (MFMA): pooled_part[mc][b][r] = sum_{p in m-chunk} hswish(BN(x@w1))
// Round 9: pre-packed bf16 tiled operands -> staging is pure global_load_lds
// DMA of CONTIGUOUS tiles (A 8 KB, B 16 KB per K-step). Zero staging VALU.
// Double-buffered, counted vmcnt(3) (never 0 in loop), 2 raw barriers/step.
// Unpadded [row][32] LDS: each MFMA frag read = sequential 1 KB span,
// conflict-free. grid (128 b, 2 mc), block 512 (8 waves 2m x 4n).
// A-tile rows 112..127 are garbage (finite) -> masked in epilogue (m<196).
// -------------------------------------------------------------------------
__global__ __launch_bounds__(512) void k_gemm_pool(
    const __bf16* __restrict__ xt,       // [b][kt][196][32]
    const __bf16* __restrict__ w1t,      // [kt][256][32]
    const float* __restrict__ g1,
    const float* __restrict__ b1,
    const float* __restrict__ m1,
    const float* __restrict__ v1,
    float* __restrict__ pooled_part)     // [2][128][256]
{
    __shared__ __bf16 Alds[2][4096];     // 128 rows x 32  (8 KB each)
    __shared__ __bf16 Blds[2][8192];     // 256 rows x 32 (16 KB each)
    __shared__ float pool_lds[2][256];

    const int b   = blockIdx.x;
    const int mc  = blockIdx.y;
    const int tid = threadIdx.x;
    const int wave = tid >> 6, lane = tid & 63;
    const int wm = wave >> 2, wn = wave & 3;   // wave grid 2(m) x 4(n)
    const int q  = lane >> 4, ln = lane & 15;
    const int nm = (wm == 0) ? 4 : 3;          // 7 m-tiles split 4 + 3

    f32x4 acc[4][4];
#pragma unroll
    for (int i = 0; i < 4; i++)
#pragma unroll
        for (int j = 0; j < 4; j++) acc[i][j] = (f32x4){0.f, 0.f, 0.f, 0.f};

    // per-lane global srcs (advance by tile stride per kt)
    const __bf16* xa = xt + ((size_t)b * 32 * 196 + (size_t)mc * 112) * 32 + tid * 8;
    const __bf16* wb = w1t + tid * 8;

    auto issue = [&](int kt, int buf) {
        gload_lds16(xa + (size_t)kt * (196 * 32), &Alds[buf][wave * 512]);
        gload_lds16(wb + (size_t)kt * 8192,       &Blds[buf][wave * 512]);
        gload_lds16(wb + (size_t)kt * 8192 + 4096, &Blds[buf][4096 + wave * 512]);
    };

    issue(0, 0);

    for (int t = 0; t < 32; ++t) {
        const int cur = t & 1;
        if (t < 31) {
            issue(t + 1, cur ^ 1);
            asm volatile("s_waitcnt vmcnt(3)" ::: "memory");   // tile t landed (mine)
        } else {
            asm volatile("s_waitcnt vmcnt(0)" ::: "memory");
        }
        __builtin_amdgcn_s_barrier();            // everyone's tile t landed
        __builtin_amdgcn_sched_barrier(0);       // no ds_read hoisting above
        bf16x8 bfr[4];
#pragma unroll
        for (int ni = 0; ni < 4; ni++)
            bfr[ni] = *(const bf16x8*)&Blds[cur][(((wn * 4 + ni) * 16 + ln) * 32) + q * 8];
#pragma unroll
        for (int mi = 0; mi < 4; mi++) {
            if (mi < nm) {
                const bf16x8 af =
                    *(const bf16x8*)&Alds[cur][(((wm * 4 + mi) * 16 + ln) * 32) + q * 8];
#pragma unroll
                for (int ni = 0; ni < 4; ni++)
                    acc[mi][ni] = __builtin_amdgcn_mfma_f32_16x16x32_bf16(
                        af, bfr[ni], acc[mi][ni], 0, 0, 0);
            }
        }
        __builtin_amdgcn_sched_barrier(0);       // no ds_read sinking below
        __builtin_amdgcn_s_barrier();            // reads done -> buf reusable
    }

    // ---- epilogue: BN + hardswish + partial pool (mask p >= 196) ----
    float psum[4] = {0.f, 0.f, 0.f, 0.f};
#pragma unroll
    for (int ni = 0; ni < 4; ni++) {
        const int r = (wn * 4 + ni) * 16 + ln;
        const float s1 = g1[r] * rsqrtf(v1[r] + EPS_F);
        const float mu = m1[r];
        const float be = b1[r];
#pragma unroll
        for (int mi = 0; mi < 4; mi++) {
            if (mi < nm) {
#pragma unroll
                for (int i = 0; i < 4; i++) {
                    const int m = mc * 112 + (wm * 4 + mi) * 16 + q * 4 + i;
                    if (m < 196) {
                        float v = acc[mi][ni][i];
                        v = (v - mu) * s1 + be;
                        const float g = fminf(fmaxf(v + 3.f, 0.f), 6.f);
                        psum[ni] += v * g * (1.f / 6.f);
                    }
                }
            }
        }
    }
#pragma unroll
    for (int ni = 0; ni < 4; ni++) {
        psum[ni] += __shfl_xor(psum[ni], 16, 64);
        psum[ni] += __shfl_xor(psum[ni], 32, 64);
    }
    if (lane < 16) {
#pragma unroll
        for (int ni = 0; ni < 4; ni++)
            pool_lds[wm][(wn * 4 + ni) * 16 + lane] = psum[ni];
    }
    __syncthreads();
    if (tid < 256)
        pooled_part[(size_t)mc * (128 * 256) + b * 256 + tid] =
            (pool_lds[0][tid] + pool_lds[1][tid]) * (1.f / 196.f);
}

// -------------------------------------------------------------------------
// Kernel 2: logits = (part0+part1) @ w2^T; BN2; sigmoid -> roi [128][6] f32
// grid 128, block 64.
// -------------------------------------------------------------------------
__global__ __launch_bounds__(64) void k_logits(
    const float* __restrict__ pooled_part,   // [2][128][256]
    const float* __restrict__ w2,
    const float* __restrict__ g2,
    const float* __restrict__ b2,
    const float* __restrict__ m2,
    const float* __restrict__ v2,
    float* __restrict__ roi)
{
    const int b = blockIdx.x, t = threadIdx.x;
    const float4 pa = ((const float4*)(pooled_part + b * 256))[t];
    const float4 pb = ((const float4*)(pooled_part + 128 * 256 + b * 256))[t];
    float4 p4;
    p4.x = pa.x + pb.x; p4.y = pa.y + pb.y;
    p4.z = pa.z + pb.z; p4.w = pa.w + pb.w;
    float part[6];
#pragma unroll
    for (int j = 0; j < 6; j++) {
        const float4 w = *(const float4*)(w2 + j * 256 + t * 4);
        part[j] = p4.x * w.x + p4.y * w.y + p4.z * w.z + p4.w * w.w;
    }
#pragma unroll
    for (int j = 0; j < 6; j++)
#pragma unroll
        for (int off = 32; off >= 1; off >>= 1)
            part[j] += __shfl_xor(part[j], off, 64);
    if (t == 0) {
        const float SC[3] = {7.f, 7.f, 4.f};
        float raw[6];
#pragma unroll
        for (int j = 0; j < 6; j++) {
            float l = part[j];
            const float s = g2[j] * rsqrtf(v2[j] + EPS_F);
            l = (l - m2[j]) * s + b2[j];
            raw[j] = 1.f / (1.f + expf(-l));
        }
#pragma unroll
        for (int d = 0; d < 3; d++) {
            roi[b * 6 + d]     = 0.5f * raw[d] * SC[d];             // start (x,y,t)
            roi[b * 6 + 3 + d] = (1.f - 0.5f * raw[3 + d]) * SC[d]; // end
        }
    }
}

__device__ __forceinline__ void prep1(float s, float e, int n, int size, int i,
                                      int& lo, int& hi, float& w0, float& w1)
{
    const float bsz = (e - s) / (float)n;
    float c = s + ((float)i + 0.5f) * bsz;
    const float valid = (c >= -1.f && c <= (float)size) ? 1.f : 0.f;
    c = fminf(fmaxf(c, 0.f), (float)(size - 1));
    lo = (int)floorf(c);
    hi = min(lo + 1, size - 1);
    const float f = c - (float)lo;
    w0 = (1.f - f) * valid;
    w1 = f * valid;
}

// -------------------------------------------------------------------------
// Kernel 3: ROI-align 3D. Block = (b, 32 channels): stage channels in LDS,
// precompute 75x8 (offset, weight) tables (transposed [8][80] -> conflict-
// free reads), then 8 LDS-FMA per output. grid (128, 32), block 256.
// -------------------------------------------------------------------------
__global__ __launch_bounds__(256) void k_roi(
    const float* __restrict__ x,
    const float* __restrict__ roi,
    float* __restrict__ out)
{
    __shared__ float xs[32 * 200];   // 32 ch x 196 (pad 200)  25.6 KiB
    __shared__ int   soff[8][80];    // sample flat offsets (po-major)
    __shared__ float swt[8][80];     // sample weights

    const int b = blockIdx.x, c0 = blockIdx.y * 32;
    const int tid = threadIdx.x;

    // ---- stage 32 channels, coalesced float4 (196 = 49*4) ----
    const float* xb = x + ((size_t)b * 1024 + c0) * 196;
#pragma unroll
    for (int k = 0; k < 7; k++) {
        const int i4 = tid + k * 256;
        if (i4 < 1568) {                       // 32*49
            const int c = i4 / 49, pq = i4 % 49;
            const float4 v = *(const float4*)(xb + c * 196 + pq * 4);
            *(float4*)&xs[c * 200 + pq * 4] = v;
        }
    }
    // ---- weight/offset tables (75 threads) ----
    if (tid < 75) {
        const int po = tid;
        const int to = po / 25, rem = po % 25, yo = rem / 5, xo = rem % 5;
        const float sx = roi[b * 6 + 0], ex = roi[b * 6 + 3];
        const float sy = roi[b * 6 + 1], ey = roi[b * 6 + 4];
        const float st = roi[b * 6 + 2], et = roi[b * 6 + 5];
        int tl, th, yl, yh, xl, xh;
        float tw0, tw1, yw0, yw1, xw0, xw1;
        prep1(st, et, 3, 4, to, tl, th, tw0, tw1);
        prep1(sy, ey, 5, 7, yo, yl, yh, yw0, yw1);
        prep1(sx, ex, 5, 7, xo, xl, xh, xw0, xw1);
#pragma unroll
        for (int s = 0; s < 8; s++) {
            const int   ti = (s & 4) ? th : tl;
            const int   yi = (s & 2) ? yh : yl;
            const int   xi = (s & 1) ? xh : xl;
            const float w = ((s & 4) ? tw1 : tw0) *
                            ((s & 2) ? yw1 : yw0) *
                            ((s & 1) ? xw1 : xw0);
            soff[s][po] = ti * 49 + yi * 7 + xi;
            swt[s][po]  = w;
        }
    }
    __syncthreads();

    // ---- compute: 32*75 = 2400 outputs ----
    const size_t obase = ((size_t)b * 1024 + c0) * 75;
#pragma unroll
    for (int k = 0; k < 10; k++) {
        const int e = tid + k * 256;
        if (e < 2400) {
            const int c = e / 75, po = e % 75;
            const float* row = &xs[c * 200];
            float v = 0.f;
#pragma unroll
            for (int s = 0; s < 8; s++)
                v += swt[s][po] * row[soff[s][po]];
            out[obase + e] = v;     // e == c*75+po: fully coalesced
        }
    }
}

extern "C" void kernel_launch(void* const* d_in, const int* in_sizes, int n_in,
                              void* d_out, int out_size, void* d_ws, size_t ws_size,
                              hipStream_t stream)
{
    const float* x  = (const float*)d_in[0];
    const float* w1 = (const float*)d_in[1];
    const float* g1 = (const float*)d_in[2];
    const float* b1 = (const float*)d_in[3];
    const float* m1 = (const float*)d_in[4];
    const float* v1 = (const float*)d_in[5];
    const float* w2 = (const float*)d_in[6];
    const float* g2 = (const float*)d_in[7];
    const float* b2 = (const float*)d_in[8];
    const float* m2 = (const float*)d_in[9];
    const float* v2 = (const float*)d_in[10];

    // workspace layout (bytes):
    //   x_t2 : 128*32*196*32*2 = 51,380,224  (+8192 OOB pad for last-tile DMA)
    //   w1_t : 32*256*32*2     =    524,288
    //   pooled_part : 2*128*256*4 = 262,144
    //   roi  : 128*6*4
    char* wsb = (char*)d_ws;
    __bf16* xt     = (__bf16*)wsb;
    __bf16* w1t    = (__bf16*)(wsb + 51388416);
    float*  pooled = (float*)(wsb + 51912704);
    float*  roi    = (float*)(wsb + 52174848);
    float*  out    = (float*)d_out;

    k_pack_w1<<<128, 256, 0, stream>>>(w1, w1t);
    k_pack_x<<<dim3(128, 32), 256, 0, stream>>>(x, xt);
    k_gemm_pool<<<dim3(128, 2), 512, 0, stream>>>(xt, w1t, g1, b1, m1, v1, pooled);
    k_logits<<<128, 64, 0, stream>>>(pooled, w2, g2, b2, m2, v2, roi);
    k_roi<<<dim3(128, 32), 256, 0, stream>>>(x, roi, out);
}